// Round 6
// baseline (166.755 us; speedup 1.0000x reference)
//
#include <hip/hip_runtime.h>

// Shapes: v (8,128,128,128) f32 | k1 (32,128,4,4) | k2 (32,128,4,4)
// conv_w (128,128) | conv_b (128) | bias (128,1,1) | out (8,128,128,128) f32
// ws (bytes): S f32[16384] @0, T f32[16384] @65536, Wh bf16[16384] @131072,
//             Wl bf16[16384] @163840, VT bf16[8*128*16384] @196608 (32 MB)
//
// Pipeline (all plain launches, graph-capture-safe):
//   kA: S[b][i][pq] = sum_{h,w} wy[h,p] wx[w,q] v[b,i,h,w]        (proven r2)
//   kT: VT[(b,h)] = bf16-transposed-swizzled image of v[b,:,h,:]  (new)
//   kB: vr -> T (+conv_b+bias folded), W -> bf16 hi/lo fragments  (proven r2)
//   kC: MFMA GEMM with B-fragments straight from VT (L2-hot) + bilinear(T)

typedef __attribute__((ext_vector_type(8))) short bf16x8;
typedef __attribute__((ext_vector_type(4))) float f32x4;
typedef unsigned int u32;
typedef unsigned short u16;

static __device__ __forceinline__ u16 f2bf(float x) {
    union { float f; u32 u; } a; a.f = x;
    u32 r = a.u + 0x7fffu + ((a.u >> 16) & 1u);   // RNE
    return (u16)(r >> 16);
}
static __device__ __forceinline__ float bf2f(u16 h) {
    union { u32 u; float f; } a; a.u = ((u32)h) << 16;
    return a.f;
}

// ---------------- Kernel A: S[b][i][pq] = sum_{h,w} wy[h,p] wx[w,q] v[b,i,h,w]
__global__ __launch_bounds__(256) void kA_reduceS(const float* __restrict__ v,
                                                  float* __restrict__ S)
{
    int bid = blockIdx.x;            // 0..1023 -> (b, i)
    const float* img = v + ((size_t)bid << 14);
    int tid  = threadIdx.x;
    int wave = tid >> 6, lane = tid & 63;

    int w0 = lane * 2;
    float wxA[4], wxB[4];
    {
        float t0 = (w0 + 0.5f) * (3.0f / 128.0f);
        int j0 = (int)t0; j0 = j0 > 2 ? 2 : j0;
        float f0 = t0 - (float)j0;
        float t1 = (w0 + 1.5f) * (3.0f / 128.0f);
        int j1 = (int)t1; j1 = j1 > 2 ? 2 : j1;
        float f1 = t1 - (float)j1;
#pragma unroll
        for (int q = 0; q < 4; ++q) {
            wxA[q] = (q == j0) ? (1.0f - f0) : ((q == j0 + 1) ? f0 : 0.0f);
            wxB[q] = (q == j1) ? (1.0f - f1) : ((q == j1 + 1) ? f1 : 0.0f);
        }
    }

    float acc[4][4] = {};
#pragma unroll 4
    for (int h = wave; h < 128; h += 4) {
        float2 px = *(const float2*)(img + h * 128 + w0);
        float part[4];
#pragma unroll
        for (int q = 0; q < 4; ++q) part[q] = px.x * wxA[q] + px.y * wxB[q];
        float t = (h + 0.5f) * (3.0f / 128.0f);
        int i0 = (int)t; i0 = i0 > 2 ? 2 : i0;
        float fr = t - (float)i0;
#pragma unroll
        for (int p = 0; p < 4; ++p) {
            float wyp = (p == i0) ? (1.0f - fr) : ((p == i0 + 1) ? fr : 0.0f);
#pragma unroll
            for (int q = 0; q < 4; ++q) acc[p][q] += wyp * part[q];
        }
    }

#pragma unroll
    for (int p = 0; p < 4; ++p)
#pragma unroll
        for (int q = 0; q < 4; ++q) {
            float s = acc[p][q];
#pragma unroll
            for (int m = 32; m >= 1; m >>= 1) s += __shfl_xor(s, m, 64);
            acc[p][q] = s;
        }

    __shared__ float red[4][16];
    if (lane == 0) {
#pragma unroll
        for (int p = 0; p < 4; ++p)
#pragma unroll
            for (int q = 0; q < 4; ++q) red[wave][p * 4 + q] = acc[p][q];
    }
    __syncthreads();
    if (tid < 16) {
        float s = red[0][tid] + red[1][tid] + red[2][tid] + red[3][tid];
        S[(bid << 4) + tid] = s;
    }
}

// ---------------- Kernel T: pre-transpose v[b,:,h,:] -> VT bf16 swizzled
__global__ __launch_bounds__(256) void kT_transpose(const float* __restrict__ v,
                                                    u16* __restrict__ VT)
{
    __shared__ u16 vt[16384];   // 32 KB: vt[w][i] bf16, XOR-swizzled 16B chunks

    int h = blockIdx.x, b = blockIdx.y;
    int tid = threadIdx.x;
    const float* vb = v + ((size_t)b << 21) + h * 128;

    // stage v[:, h, :] -> LDS transposed bf16 with swizzle (proven r2 code)
    {
        int w = tid & 127, ib = tid >> 7;
        unsigned sw = (unsigned)(w & 15);
        unsigned rowbase = (unsigned)w * 256 + (unsigned)ib * 8;
#pragma unroll
        for (int it = 0; it < 16; ++it) {
            int i0 = it * 8 + ib * 4;
            float x0 = vb[(size_t)(i0 + 0) * 16384 + w];
            float x1 = vb[(size_t)(i0 + 1) * 16384 + w];
            float x2 = vb[(size_t)(i0 + 2) * 16384 + w];
            float x3 = vb[(size_t)(i0 + 3) * 16384 + w];
            u32 p0 = (u32)f2bf(x0) | ((u32)f2bf(x1) << 16);
            u32 p1 = (u32)f2bf(x2) | ((u32)f2bf(x3) << 16);
            unsigned byteoff = rowbase + ((((unsigned)it) ^ sw) << 4);
            *(uint2*)((char*)vt + byteoff) = make_uint2(p0, p1);
        }
    }
    __syncthreads();

    // linear copy LDS -> VT (coalesced 1KB/wave stores)
    uint4* dst = (uint4*)(VT + ((size_t)(b * 128 + h) << 14));
    const uint4* src = (const uint4*)vt;
#pragma unroll
    for (int k = 0; k < 8; ++k)
        dst[tid + 256 * k] = src[tid + 256 * k];
}

// ---------------- Kernel B: vr -> T (+conv_b+bias folded), W -> bf16 hi/lo frags
__global__ __launch_bounds__(256) void kB_small(const float* __restrict__ S,
                                                const float* __restrict__ k1,
                                                const float* __restrict__ k2,
                                                const float* __restrict__ conv_w,
                                                const float* __restrict__ conv_b,
                                                const float* __restrict__ bias,
                                                float* __restrict__ T,
                                                u16* __restrict__ Wh,
                                                u16* __restrict__ Wl)
{
    int b = blockIdx.x;
    int tid = threadIdx.x;
    __shared__ float Ss[2048];
    __shared__ float vrs[32];

    const float* Sb = S + b * 2048;
#pragma unroll
    for (int it = 0; it < 2; ++it) {
        int f = (it * 256 + tid) * 4;
        *(float4*)&Ss[f] = *(const float4*)&Sb[f];
    }
    __syncthreads();

    {
        int r = tid >> 3, j = tid & 7;
        const float* k1r = k1 + r * 2048 + j * 256;
        const float* Sj  = Ss + j * 256;
        float partial = 0.0f;
#pragma unroll 4
        for (int e = 0; e < 256; e += 4) {
            float4 a  = *(const float4*)&k1r[e];
            float4 s4 = *(const float4*)&Sj[e];
            partial += a.x * s4.x + a.y * s4.y + a.z * s4.z + a.w * s4.w;
        }
        partial += __shfl_xor(partial, 1, 64);
        partial += __shfl_xor(partial, 2, 64);
        partial += __shfl_xor(partial, 4, 64);
        if (j == 0) vrs[r] = partial * (1.0f / 16384.0f);
    }
    __syncthreads();

    {
        int f0 = tid * 8;
        int o  = tid >> 1;
        float cb = conv_b[o] + bias[o];
        float acc[8] = {};
        for (int rr = 0; rr < 32; ++rr) {
            float vv = vrs[rr];
            const float* k2r = k2 + rr * 2048 + f0;
            float4 a0 = *(const float4*)&k2r[0];
            float4 a1 = *(const float4*)&k2r[4];
            acc[0] += vv * a0.x; acc[1] += vv * a0.y;
            acc[2] += vv * a0.z; acc[3] += vv * a0.w;
            acc[4] += vv * a1.x; acc[5] += vv * a1.y;
            acc[6] += vv * a1.z; acc[7] += vv * a1.w;
        }
        float* Tb = T + b * 2048 + f0;
        float4 r0, r1;
        r0.x = acc[0] + cb; r0.y = acc[1] + cb; r0.z = acc[2] + cb; r0.w = acc[3] + cb;
        r1.x = acc[4] + cb; r1.y = acc[5] + cb; r1.z = acc[6] + cb; r1.w = acc[7] + cb;
        *(float4*)&Tb[0] = r0;
        *(float4*)&Tb[4] = r1;
    }

    {
        int ks = tid >> 6, l = tid & 63;
        int o = (b << 4) + (l & 15);
        int ibase = ks * 32 + ((l >> 4) << 3);
        const float* src = conv_w + o * 128 + ibase;
        float4 c0 = *(const float4*)src;
        float4 c1 = *(const float4*)(src + 4);
        float xs[8] = {c0.x, c0.y, c0.z, c0.w, c1.x, c1.y, c1.z, c1.w};
        union { u16 s[8]; bf16x8 v; } ph, pl;
#pragma unroll
        for (int j = 0; j < 8; ++j) {
            u16 hi = f2bf(xs[j]);
            ph.s[j] = hi;
            pl.s[j] = f2bf(xs[j] - bf2f(hi));
        }
        int didx = (((b * 4 + ks) * 64) + l) * 8;
        *(bf16x8*)(Wh + didx) = ph.v;
        *(bf16x8*)(Wl + didx) = pl.v;
    }
}

// ---------------- Kernel C: MFMA GEMM, B-fragments direct from VT (L2-hot)
__global__ __launch_bounds__(256, 4) void kC_mfma(const u16* __restrict__ VT,
                                                  const u16* __restrict__ Wh,
                                                  const u16* __restrict__ Wl,
                                                  const float* __restrict__ T,
                                                  float* __restrict__ out)
{
    __shared__ float U[128][4];

    int h = blockIdx.x, b = blockIdx.y;
    int tid = threadIdx.x;
    int lane = tid & 63, wid = tid >> 6;

    const char* vtg = (const char*)(VT + ((size_t)(b * 128 + h) << 14));

    // U[o][q] = sum_p wy[h,p] * T[b][o][p][q]  (overlaps MFMA; sync is below)
    {
        float t = (h + 0.5f) * (3.0f / 128.0f);
        int i0 = (int)t; i0 = i0 > 2 ? 2 : i0;
        float fr = t - (float)i0;
        if (tid < 128) {
            const float* Tb = T + b * 2048 + tid * 16;
            float4 r0 = *(const float4*)&Tb[0];
            float4 r1 = *(const float4*)&Tb[4];
            float4 r2 = *(const float4*)&Tb[8];
            float4 r3 = *(const float4*)&Tb[12];
            float wy0 = (i0 == 0) ? (1.0f - fr) : 0.0f;
            float wy1 = (i0 == 1) ? (1.0f - fr) : ((i0 == 0) ? fr : 0.0f);
            float wy2 = (i0 == 2) ? (1.0f - fr) : ((i0 == 1) ? fr : 0.0f);
            float wy3 = (i0 == 2) ? fr : 0.0f;
            U[tid][0] = wy0 * r0.x + wy1 * r1.x + wy2 * r2.x + wy3 * r3.x;
            U[tid][1] = wy0 * r0.y + wy1 * r1.y + wy2 * r2.y + wy3 * r3.y;
            U[tid][2] = wy0 * r0.z + wy1 * r1.z + wy2 * r2.z + wy3 * r3.z;
            U[tid][3] = wy0 * r0.w + wy1 * r1.w + wy2 * r2.w + wy3 * r3.w;
        }
    }

    int mh = wid >> 1, nh = wid & 1;
    int g = lane >> 4, ln = lane & 15;

    f32x4 acc[4][4];
#pragma unroll
    for (int mt = 0; mt < 4; ++mt)
#pragma unroll
        for (int nt = 0; nt < 4; ++nt)
            acc[mt][nt] = (f32x4){0.f, 0.f, 0.f, 0.f};

#pragma unroll
    for (int ks = 0; ks < 4; ++ks) {
        bf16x8 Ah[4], Al[4], Bf[4];
#pragma unroll
        for (int mt = 0; mt < 4; ++mt) {
            int idx = ((((mh * 4 + mt) * 4 + ks) * 64) + lane) * 8;
            Ah[mt] = *(const bf16x8*)(Wh + idx);
            Al[mt] = *(const bf16x8*)(Wl + idx);
        }
#pragma unroll
        for (int nt = 0; nt < 4; ++nt) {
            unsigned wrow = (unsigned)(nh * 64 + nt * 16 + ln);
            unsigned byteoff = wrow * 256 + ((((unsigned)(ks * 4 + g)) ^ (unsigned)ln) << 4);
            Bf[nt] = *(const bf16x8*)(vtg + byteoff);
        }
#pragma unroll
        for (int nt = 0; nt < 4; ++nt)
#pragma unroll
            for (int mt = 0; mt < 4; ++mt) {
                acc[mt][nt] = __builtin_amdgcn_mfma_f32_16x16x32_bf16(Ah[mt], Bf[nt], acc[mt][nt], 0, 0, 0);
                acc[mt][nt] = __builtin_amdgcn_mfma_f32_16x16x32_bf16(Al[mt], Bf[nt], acc[mt][nt], 0, 0, 0);
            }
    }

    __syncthreads();   // U ready (written by tid<128 above)

    float wqa[4][4];
#pragma unroll
    for (int nt = 0; nt < 4; ++nt) {
        int wn = nh * 64 + nt * 16 + ln;
        float tw = (wn + 0.5f) * (3.0f / 128.0f);
        int j0 = (int)tw; j0 = j0 > 2 ? 2 : j0;
        float fw = tw - (float)j0;
        wqa[nt][0] = (j0 == 0) ? (1.0f - fw) : 0.0f;
        wqa[nt][1] = (j0 == 1) ? (1.0f - fw) : ((j0 == 0) ? fw : 0.0f);
        wqa[nt][2] = (j0 == 2) ? (1.0f - fw) : ((j0 == 1) ? fw : 0.0f);
        wqa[nt][3] = (j0 == 2) ? fw : 0.0f;
    }

    float* ob = out + ((size_t)b << 21) + h * 128;
#pragma unroll
    for (int mt = 0; mt < 4; ++mt) {
#pragma unroll
        for (int r = 0; r < 4; ++r) {
            int o = mh * 64 + mt * 16 + g * 4 + r;
            float4 Uo = *(const float4*)&U[o][0];
            float* orow = ob + (size_t)o * 16384;
#pragma unroll
            for (int nt = 0; nt < 4; ++nt) {
                int wn = nh * 64 + nt * 16 + ln;
                orow[wn] = acc[mt][nt][r] + wqa[nt][0] * Uo.x + wqa[nt][1] * Uo.y
                                          + wqa[nt][2] * Uo.z + wqa[nt][3] * Uo.w;
            }
        }
    }
}

extern "C" void kernel_launch(void* const* d_in, const int* in_sizes, int n_in,
                              void* d_out, int out_size, void* d_ws, size_t ws_size,
                              hipStream_t stream) {
    const float* v      = (const float*)d_in[0];
    const float* k1     = (const float*)d_in[1];
    const float* k2     = (const float*)d_in[2];
    const float* conv_w = (const float*)d_in[3];
    const float* conv_b = (const float*)d_in[4];
    const float* bias   = (const float*)d_in[5];
    float* out = (float*)d_out;

    float* S  = (float*)d_ws;                          // 16384 f32
    float* T  = (float*)((char*)d_ws + 65536);         // 16384 f32
    u16*   Wh = (u16*)((char*)d_ws + 131072);          // 16384 bf16
    u16*   Wl = (u16*)((char*)d_ws + 163840);          // 16384 bf16
    u16*   VT = (u16*)((char*)d_ws + 196608);          // 8*128*16384 bf16 = 32 MB

    kA_reduceS<<<1024, 256, 0, stream>>>(v, S);
    kT_transpose<<<dim3(128, 8), 256, 0, stream>>>(v, VT);
    kB_small<<<8, 256, 0, stream>>>(S, k1, k2, conv_w, conv_b, bias, T, Wh, Wl);
    kC_mfma<<<dim3(128, 8), 256, 0, stream>>>(VT, Wh, Wl, T, out);
}

// Round 8
// 154.603 us; speedup vs baseline: 1.0786x; 1.0786x over previous
//
#include <hip/hip_runtime.h>

// Shapes: v (8,128,128,128) f32 | k1 (32,128,4,4) | k2 (32,128,4,4)
// conv_w (128,128) | conv_b (128) | bias (128,1,1) | out (8,128,128,128) f32
// ws (bytes): S f32[16384] @0, T f32[16384] @65536, Wh bf16[16384] @131072,
//             Wl bf16[16384] @163840
//
// Proven round-2 pipeline (155.8 us, absmax 0.0156):
//   kA: S[b][i][pq] = sum_{h,w} wy[h,p] wx[w,q] v[b,i,h,w]
//   kB: vr -> T (+conv_b+bias folded), W -> bf16 hi/lo MFMA A-fragments
//   kC: MFMA GEMM (W as A-operand, v as B-operand) + bilinear(T) epilogue
// NOTE: do NOT swap MFMA operand roles (r7: absmax 0.121 — A/B slot
// mappings are not transpose-symmetric on gfx950).

typedef __attribute__((ext_vector_type(8))) short bf16x8;
typedef __attribute__((ext_vector_type(4))) float f32x4;
typedef unsigned int u32;
typedef unsigned short u16;

static __device__ __forceinline__ u16 f2bf(float x) {
    union { float f; u32 u; } a; a.f = x;
    u32 r = a.u + 0x7fffu + ((a.u >> 16) & 1u);   // RNE
    return (u16)(r >> 16);
}
static __device__ __forceinline__ float bf2f(u16 h) {
    union { u32 u; float f; } a; a.u = ((u32)h) << 16;
    return a.f;
}

// ---------------- Kernel A: S[b][i][pq] = sum_{h,w} wy[h,p] wx[w,q] v[b,i,h,w]
__global__ __launch_bounds__(256) void kA_reduceS(const float* __restrict__ v,
                                                  float* __restrict__ S)
{
    int bid = blockIdx.x;            // 0..1023 -> (b, i)
    const float* img = v + ((size_t)bid << 14);
    int tid  = threadIdx.x;
    int wave = tid >> 6, lane = tid & 63;

    int w0 = lane * 2;
    float wxA[4], wxB[4];
    {
        float t0 = (w0 + 0.5f) * (3.0f / 128.0f);
        int j0 = (int)t0; j0 = j0 > 2 ? 2 : j0;
        float f0 = t0 - (float)j0;
        float t1 = (w0 + 1.5f) * (3.0f / 128.0f);
        int j1 = (int)t1; j1 = j1 > 2 ? 2 : j1;
        float f1 = t1 - (float)j1;
#pragma unroll
        for (int q = 0; q < 4; ++q) {
            wxA[q] = (q == j0) ? (1.0f - f0) : ((q == j0 + 1) ? f0 : 0.0f);
            wxB[q] = (q == j1) ? (1.0f - f1) : ((q == j1 + 1) ? f1 : 0.0f);
        }
    }

    float acc[4][4] = {};
#pragma unroll 4
    for (int h = wave; h < 128; h += 4) {
        float2 px = *(const float2*)(img + h * 128 + w0);
        float part[4];
#pragma unroll
        for (int q = 0; q < 4; ++q) part[q] = px.x * wxA[q] + px.y * wxB[q];
        float t = (h + 0.5f) * (3.0f / 128.0f);
        int i0 = (int)t; i0 = i0 > 2 ? 2 : i0;
        float fr = t - (float)i0;
#pragma unroll
        for (int p = 0; p < 4; ++p) {
            float wyp = (p == i0) ? (1.0f - fr) : ((p == i0 + 1) ? fr : 0.0f);
#pragma unroll
            for (int q = 0; q < 4; ++q) acc[p][q] += wyp * part[q];
        }
    }

#pragma unroll
    for (int p = 0; p < 4; ++p)
#pragma unroll
        for (int q = 0; q < 4; ++q) {
            float s = acc[p][q];
#pragma unroll
            for (int m = 32; m >= 1; m >>= 1) s += __shfl_xor(s, m, 64);
            acc[p][q] = s;
        }

    __shared__ float red[4][16];
    if (lane == 0) {
#pragma unroll
        for (int p = 0; p < 4; ++p)
#pragma unroll
            for (int q = 0; q < 4; ++q) red[wave][p * 4 + q] = acc[p][q];
    }
    __syncthreads();
    if (tid < 16) {
        float s = red[0][tid] + red[1][tid] + red[2][tid] + red[3][tid];
        S[(bid << 4) + tid] = s;
    }
}

// ---------------- Kernel B: vr -> T (+conv_b+bias folded), W -> bf16 hi/lo frags
__global__ __launch_bounds__(256) void kB_small(const float* __restrict__ S,
                                                const float* __restrict__ k1,
                                                const float* __restrict__ k2,
                                                const float* __restrict__ conv_w,
                                                const float* __restrict__ conv_b,
                                                const float* __restrict__ bias,
                                                float* __restrict__ T,
                                                u16* __restrict__ Wh,
                                                u16* __restrict__ Wl)
{
    int b = blockIdx.x;    // 0..7
    int tid = threadIdx.x; // 0..255
    __shared__ float Ss[2048];
    __shared__ float vrs[32];

    const float* Sb = S + b * 2048;
#pragma unroll
    for (int it = 0; it < 2; ++it) {
        int f = (it * 256 + tid) * 4;
        *(float4*)&Ss[f] = *(const float4*)&Sb[f];
    }
    __syncthreads();

    // vr[r] = (1/16384) * sum_{2048} k1[r][.] * S[b][.]
    {
        int r = tid >> 3, j = tid & 7;
        const float* k1r = k1 + r * 2048 + j * 256;
        const float* Sj  = Ss + j * 256;
        float partial = 0.0f;
#pragma unroll 4
        for (int e = 0; e < 256; e += 4) {
            float4 a  = *(const float4*)&k1r[e];
            float4 s4 = *(const float4*)&Sj[e];
            partial += a.x * s4.x + a.y * s4.y + a.z * s4.z + a.w * s4.w;
        }
        partial += __shfl_xor(partial, 1, 64);
        partial += __shfl_xor(partial, 2, 64);
        partial += __shfl_xor(partial, 4, 64);
        if (j == 0) vrs[r] = partial * (1.0f / 16384.0f);
    }
    __syncthreads();

    // T[b][o][pq] = sum_r k2[r][o][pq]*vr[r]  (+ conv_b[o] + bias[o])
    {
        int f0 = tid * 8;
        int o  = tid >> 1;
        float cb = conv_b[o] + bias[o];
        float acc[8] = {};
        for (int rr = 0; rr < 32; ++rr) {
            float vv = vrs[rr];
            const float* k2r = k2 + rr * 2048 + f0;
            float4 a0 = *(const float4*)&k2r[0];
            float4 a1 = *(const float4*)&k2r[4];
            acc[0] += vv * a0.x; acc[1] += vv * a0.y;
            acc[2] += vv * a0.z; acc[3] += vv * a0.w;
            acc[4] += vv * a1.x; acc[5] += vv * a1.y;
            acc[6] += vv * a1.z; acc[7] += vv * a1.w;
        }
        float* Tb = T + b * 2048 + f0;
        float4 r0, r1;
        r0.x = acc[0] + cb; r0.y = acc[1] + cb; r0.z = acc[2] + cb; r0.w = acc[3] + cb;
        r1.x = acc[4] + cb; r1.y = acc[5] + cb; r1.z = acc[6] + cb; r1.w = acc[7] + cb;
        *(float4*)&Tb[0] = r0;
        *(float4*)&Tb[4] = r1;
    }

    // Packed A-fragments: Wh[((mtg*4 + ks)*64 + lane)*8 + j] = bf16(conv_w[o][i]),
    //   o = mtg*16 + (lane&15), i = ks*32 + (lane>>4)*8 + j.
    {
        int ks = tid >> 6, l = tid & 63;
        int o = (b << 4) + (l & 15);
        int ibase = ks * 32 + ((l >> 4) << 3);
        const float* src = conv_w + o * 128 + ibase;
        float4 c0 = *(const float4*)src;
        float4 c1 = *(const float4*)(src + 4);
        float xs[8] = {c0.x, c0.y, c0.z, c0.w, c1.x, c1.y, c1.z, c1.w};
        union { u16 s[8]; bf16x8 v; } ph, pl;
#pragma unroll
        for (int j = 0; j < 8; ++j) {
            u16 hi = f2bf(xs[j]);
            ph.s[j] = hi;
            pl.s[j] = f2bf(xs[j] - bf2f(hi));
        }
        int didx = (((b * 4 + ks) * 64) + l) * 8;
        *(bf16x8*)(Wh + didx) = ph.v;
        *(bf16x8*)(Wl + didx) = pl.v;
    }
}

// ---------------- Kernel C: MFMA GEMM out[b][:,h,:] = W*v + bilinear(T) epilogue
__global__ __launch_bounds__(256, 4) void kC_mfma(const float* __restrict__ v,
                                                  const u16* __restrict__ Wh,
                                                  const u16* __restrict__ Wl,
                                                  const float* __restrict__ T,
                                                  float* __restrict__ out)
{
    __shared__ u16 vt[16384];      // 32KB: vt[w][i] bf16, XOR-swizzled 16B chunks
    __shared__ float U[128][4];    // 2KB

    int h = blockIdx.x, b = blockIdx.y;
    int tid = threadIdx.x;
    int lane = tid & 63, wid = tid >> 6;

    const float* vb = v + ((size_t)b << 21) + h * 128;

    // ---- stage v[:, h, :] -> LDS transposed bf16 with swizzle
    {
        int w = tid & 127, ib = tid >> 7;
        unsigned sw = (unsigned)(w & 15);
        unsigned rowbase = (unsigned)w * 256 + (unsigned)ib * 8;
#pragma unroll
        for (int it = 0; it < 16; ++it) {
            int i0 = it * 8 + ib * 4;
            float x0 = vb[(size_t)(i0 + 0) * 16384 + w];
            float x1 = vb[(size_t)(i0 + 1) * 16384 + w];
            float x2 = vb[(size_t)(i0 + 2) * 16384 + w];
            float x3 = vb[(size_t)(i0 + 3) * 16384 + w];
            u32 p0 = (u32)f2bf(x0) | ((u32)f2bf(x1) << 16);
            u32 p1 = (u32)f2bf(x2) | ((u32)f2bf(x3) << 16);
            unsigned byteoff = rowbase + ((((unsigned)it) ^ sw) << 4);
            *(uint2*)((char*)vt + byteoff) = make_uint2(p0, p1);
        }
    }

    // ---- U[o][q] = sum_p wy[h,p] * T[b][o][p][q]
    {
        float t = (h + 0.5f) * (3.0f / 128.0f);
        int i0 = (int)t; i0 = i0 > 2 ? 2 : i0;
        float fr = t - (float)i0;
        if (tid < 128) {
            const float* Tb = T + b * 2048 + tid * 16;
            float4 r0 = *(const float4*)&Tb[0];
            float4 r1 = *(const float4*)&Tb[4];
            float4 r2 = *(const float4*)&Tb[8];
            float4 r3 = *(const float4*)&Tb[12];
            float wy0 = (i0 == 0) ? (1.0f - fr) : 0.0f;
            float wy1 = (i0 == 1) ? (1.0f - fr) : ((i0 == 0) ? fr : 0.0f);
            float wy2 = (i0 == 2) ? (1.0f - fr) : ((i0 == 1) ? fr : 0.0f);
            float wy3 = (i0 == 2) ? fr : 0.0f;
            U[tid][0] = wy0 * r0.x + wy1 * r1.x + wy2 * r2.x + wy3 * r3.x;
            U[tid][1] = wy0 * r0.y + wy1 * r1.y + wy2 * r2.y + wy3 * r3.y;
            U[tid][2] = wy0 * r0.z + wy1 * r1.z + wy2 * r2.z + wy3 * r3.z;
            U[tid][3] = wy0 * r0.w + wy1 * r1.w + wy2 * r2.w + wy3 * r3.w;
        }
    }
    __syncthreads();

    // ---- MFMA main: wave (mh, nh) owns 64o x 64w
    int mh = wid >> 1, nh = wid & 1;
    int g = lane >> 4, ln = lane & 15;

    f32x4 acc[4][4];
#pragma unroll
    for (int mt = 0; mt < 4; ++mt)
#pragma unroll
        for (int nt = 0; nt < 4; ++nt)
            acc[mt][nt] = (f32x4){0.f, 0.f, 0.f, 0.f};

#pragma unroll
    for (int ks = 0; ks < 4; ++ks) {
        bf16x8 Ah[4], Al[4];
#pragma unroll
        for (int mt = 0; mt < 4; ++mt) {
            int idx = ((((mh * 4 + mt) * 4 + ks) * 64) + lane) * 8;
            Ah[mt] = *(const bf16x8*)(Wh + idx);
            Al[mt] = *(const bf16x8*)(Wl + idx);
        }
#pragma unroll
        for (int nt = 0; nt < 4; ++nt) {
            unsigned wrow = (unsigned)(nh * 64 + nt * 16 + ln);
            unsigned byteoff = wrow * 256 + ((((unsigned)(ks * 4 + g)) ^ (unsigned)ln) << 4);
            bf16x8 Bf = *(const bf16x8*)((const char*)vt + byteoff);
#pragma unroll
            for (int mt = 0; mt < 4; ++mt) {
                acc[mt][nt] = __builtin_amdgcn_mfma_f32_16x16x32_bf16(Ah[mt], Bf, acc[mt][nt], 0, 0, 0);
                acc[mt][nt] = __builtin_amdgcn_mfma_f32_16x16x32_bf16(Al[mt], Bf, acc[mt][nt], 0, 0, 0);
            }
        }
    }

    // ---- epilogue: out[o][w] = acc + sum_q wx[w,q]*U[o][q]
    float wqa[4][4];
#pragma unroll
    for (int nt = 0; nt < 4; ++nt) {
        int wn = nh * 64 + nt * 16 + ln;
        float tw = (wn + 0.5f) * (3.0f / 128.0f);
        int j0 = (int)tw; j0 = j0 > 2 ? 2 : j0;
        float fw = tw - (float)j0;
        wqa[nt][0] = (j0 == 0) ? (1.0f - fw) : 0.0f;
        wqa[nt][1] = (j0 == 1) ? (1.0f - fw) : ((j0 == 0) ? fw : 0.0f);
        wqa[nt][2] = (j0 == 2) ? (1.0f - fw) : ((j0 == 1) ? fw : 0.0f);
        wqa[nt][3] = (j0 == 2) ? fw : 0.0f;
    }

    float* ob = out + ((size_t)b << 21) + h * 128;
#pragma unroll
    for (int mt = 0; mt < 4; ++mt) {
#pragma unroll
        for (int r = 0; r < 4; ++r) {
            int o = mh * 64 + mt * 16 + g * 4 + r;
            float4 Uo = *(const float4*)&U[o][0];
            float* orow = ob + (size_t)o * 16384;
#pragma unroll
            for (int nt = 0; nt < 4; ++nt) {
                int wn = nh * 64 + nt * 16 + ln;
                float res = acc[mt][nt][r] + wqa[nt][0] * Uo.x + wqa[nt][1] * Uo.y
                                           + wqa[nt][2] * Uo.z + wqa[nt][3] * Uo.w;
                orow[wn] = res;
            }
        }
    }
}

extern "C" void kernel_launch(void* const* d_in, const int* in_sizes, int n_in,
                              void* d_out, int out_size, void* d_ws, size_t ws_size,
                              hipStream_t stream) {
    const float* v      = (const float*)d_in[0];
    const float* k1     = (const float*)d_in[1];
    const float* k2     = (const float*)d_in[2];
    const float* conv_w = (const float*)d_in[3];
    const float* conv_b = (const float*)d_in[4];
    const float* bias   = (const float*)d_in[5];
    float* out = (float*)d_out;

    float* S  = (float*)d_ws;                          // 16384 f32
    float* T  = (float*)((char*)d_ws + 65536);         // 16384 f32
    u16*   Wh = (u16*)((char*)d_ws + 131072);          // 16384 bf16
    u16*   Wl = (u16*)((char*)d_ws + 163840);          // 16384 bf16

    kA_reduceS<<<1024, 256, 0, stream>>>(v, S);
    kB_small<<<8, 256, 0, stream>>>(S, k1, k2, conv_w, conv_b, bias, T, Wh, Wl);
    kC_mfma<<<dim3(128, 8), 256, 0, stream>>>(v, Wh, Wl, T, out);
}